// Round 2
// baseline (14906.747 us; speedup 1.0000x reference)
//
#include <hip/hip_runtime.h>
#include <cmath>

typedef __bf16 bf16;
typedef float f32x4 __attribute__((ext_vector_type(4)));
typedef bf16 bf16x8 __attribute__((ext_vector_type(8)));

#define DEVINL __device__ __forceinline__

DEVINL void gload_lds16(const void* g, void* l) {
  __builtin_amdgcn_global_load_lds(
      (const __attribute__((address_space(1))) void*)g,
      (__attribute__((address_space(3))) void*)l, 16, 0, 0);
}

DEVINL float sigf(float x) { return 1.f / (1.f + __expf(-x)); }

// ---------------- cast / prep kernels ----------------
__global__ void cast_bf_k(const float* __restrict__ in, bf16* __restrict__ out, int n) {
  int i = blockIdx.x * blockDim.x + threadIdx.x;
  if (i < n) out[i] = (bf16)in[i];
}

__global__ void prep_x_k(const float* __restrict__ x, bf16* __restrict__ xe,
                         bf16* __restrict__ xd) {
  int idx = blockIdx.x * blockDim.x + threadIdx.x;  // T*B*I = 4194304
  if (idx >= 128 * 64 * 512) return;
  int i = idx & 511;
  int b = (idx >> 9) & 63;
  int t = idx >> 15;
  xe[idx] = (bf16)x[(size_t)b * 65536 + (size_t)t * 512 + i];
  xd[idx] = (t == 0) ? (bf16)0.f
                     : (bf16)x[(size_t)b * 65536 + (size_t)(t - 1) * 512 + i];
}

__global__ void zero_bars_k(unsigned* b) {
  if (threadIdx.x < 8) b[threadIdx.x] = 0;
}

// ---------------- big GEMM: C[M,N] = A[M,K] @ W[N,K]^T (bf16 in, f32 acc) ----------
__global__ __launch_bounds__(256) void gemm_bt_k(
    const bf16* __restrict__ A, const bf16* __restrict__ Bw,
    bf16* __restrict__ Cbf, float* __restrict__ Cf32, const float* __restrict__ bias,
    int M, int N, int K, int mode) {
  __shared__ __attribute__((aligned(16))) bf16 As[128 * 32];
  __shared__ __attribute__((aligned(16))) bf16 Bs[128 * 32];
  const int tid = threadIdx.x;
  const int lane = tid & 63;
  const int wave = tid >> 6;
  const int wm = wave >> 1, wn = wave & 1;
  const int m0 = blockIdx.y * 128;
  const int n0 = blockIdx.x * 128;

  f32x4 acc[4][4];
  for (int i = 0; i < 4; ++i)
    for (int j = 0; j < 4; ++j) acc[i][j] = 0;

  const int r1 = tid >> 2;
  const int kc = (tid & 3) * 8;
  const int fr = lane & 15;
  const int fk = (lane >> 4) * 8;

  for (int k0 = 0; k0 < K; k0 += 32) {
    gload_lds16(A + (size_t)(m0 + r1) * K + k0 + kc, As + tid * 8);
    gload_lds16(A + (size_t)(m0 + 64 + r1) * K + k0 + kc, As + 2048 + tid * 8);
    gload_lds16(Bw + (size_t)(n0 + r1) * K + k0 + kc, Bs + tid * 8);
    gload_lds16(Bw + (size_t)(n0 + 64 + r1) * K + k0 + kc, Bs + 2048 + tid * 8);
    __syncthreads();
    bf16x8 af[4], bw[4];
    for (int i = 0; i < 4; ++i)
      af[i] = *(const bf16x8*)(As + (wm * 64 + i * 16 + fr) * 32 + fk);
    for (int j = 0; j < 4; ++j)
      bw[j] = *(const bf16x8*)(Bs + (wn * 64 + j * 16 + fr) * 32 + fk);
    for (int i = 0; i < 4; ++i)
      for (int j = 0; j < 4; ++j)
        acc[i][j] = __builtin_amdgcn_mfma_f32_16x16x32_bf16(af[i], bw[j], acc[i][j], 0, 0, 0);
    __syncthreads();
  }

  const int col16 = lane & 15;
  const int rq = (lane >> 4) * 4;
  for (int i = 0; i < 4; ++i)
    for (int j = 0; j < 4; ++j)
      for (int r = 0; r < 4; ++r) {
        int row = m0 + wm * 64 + i * 16 + rq + r;
        int col = n0 + wn * 64 + j * 16 + col16;
        float v = acc[i][j][r];
        if (mode == 0) {
          Cbf[(size_t)row * N + col] = (bf16)v;
        } else {
          v = sigf(v + bias[col]);
          int b = row & 63, t = row >> 6;
          Cf32[(size_t)b * (128 * 512) + (size_t)t * 512 + col] = v;
        }
      }
}

// ---------------- persistent LSTM sequence kernel (cooperative) ----------------
// Grid: 128 WGs x 256 thr. WG w owns hidden cols j0=w*8 (x4 gates = 32 gate-cols).
// Waves: ct = wave&1 (col-tile of 16 gate-cols), kw = wave>>1 (k-half of 512).
// Whh fragments live in registers for the whole kernel (read from global once).
// A-frags read directly from global h (previous step's output). One grid barrier
// per timestep. c-state register-resident (each WG exclusively owns its cols).
__global__ __launch_bounds__(256, 1) void lstm_seq_k(
    const bf16* __restrict__ G,      // [T*64, 4096] precomputed input-side gates
    const bf16* __restrict__ Whh,    // [4096, 1024]
    const float* __restrict__ bias,  // [4096]
    const bf16* __restrict__ h0,     // [64,1024] or nullptr (zeros)
    const float* __restrict__ c0,    // [64,1024] or nullptr (zeros)
    bf16* __restrict__ hb0, bf16* __restrict__ hb1,  // ping-pong h buffers
    bf16* __restrict__ Sout,         // [T*64,1024] or nullptr
    bf16* __restrict__ Hfin,         // bf16 tanh(h_T) or nullptr
    unsigned* __restrict__ bar, int T) {
  __shared__ float gt[2][64][33];
  const int tid = threadIdx.x;
  const int lane = tid & 63;
  const int wave = tid >> 6;
  const int ct = wave & 1;
  const int kw = wave >> 1;
  const int j0 = blockIdx.x * 8;
  const int fr = lane & 15;
  const int fk = (lane >> 4) * 8;
  const int rq = (lane >> 4) * 4;

  // B fragment rows: column ccol (0..31) -> Whh row gate*1024 + j0 + (ccol&7)
  const int ccol = ct * 16 + fr;
  const int nrow = (ccol >> 3) * 1024 + j0 + (ccol & 7);

  bf16x8 breg[16];
  {
    const bf16* wb = Whh + (size_t)nrow * 1024 + kw * 512 + fk;
#pragma unroll
    for (int kk = 0; kk < 16; ++kk) breg[kk] = *(const bf16x8*)(wb + kk * 32);
  }

  // cell mapping: thread handles (b=cb, jj=cj+r) for r in {0,1}
  const int cb = tid >> 2;
  const int cj = (tid & 3) * 2;
  float creg[2];
  if (c0) {
    creg[0] = c0[cb * 1024 + j0 + cj];
    creg[1] = c0[cb * 1024 + j0 + cj + 1];
  } else {
    creg[0] = creg[1] = 0.f;
  }
  float bsr[4][2];
#pragma unroll
  for (int g = 0; g < 4; ++g) {
    bsr[g][0] = bias[g * 1024 + j0 + cj];
    bsr[g][1] = bias[g * 1024 + j0 + cj + 1];
  }

  const int aoff = fr * 1024 + kw * 512 + fk;  // lane's A offset within h buffer
  unsigned gen = 0;
  const unsigned nwg = gridDim.x;

  for (int t = 0; t < T; ++t) {
    // prefetch this thread's input-side gate values
    const bf16* Gt = G + (size_t)t * (64 * 4096) + (size_t)cb * 4096;
    float gx[4][2];
#pragma unroll
    for (int g = 0; g < 4; ++g) {
      gx[g][0] = (float)Gt[g * 1024 + j0 + cj];
      gx[g][1] = (float)Gt[g * 1024 + j0 + cj + 1];
    }

    f32x4 acc[4];
    acc[0] = 0; acc[1] = 0; acc[2] = 0; acc[3] = 0;
    const bf16* hp = (t == 0) ? h0 : ((t & 1) ? hb0 : hb1);
    if (hp) {
      const bf16* a0p = hp + aoff;
      const bf16* a1p = a0p + 16 * 1024;
      const bf16* a2p = a0p + 32 * 1024;
      const bf16* a3p = a0p + 48 * 1024;
#pragma unroll
      for (int kk = 0; kk < 16; ++kk) {
        bf16x8 a0 = *(const bf16x8*)(a0p + kk * 32);
        bf16x8 a1 = *(const bf16x8*)(a1p + kk * 32);
        bf16x8 a2 = *(const bf16x8*)(a2p + kk * 32);
        bf16x8 a3 = *(const bf16x8*)(a3p + kk * 32);
        acc[0] = __builtin_amdgcn_mfma_f32_16x16x32_bf16(a0, breg[kk], acc[0], 0, 0, 0);
        acc[1] = __builtin_amdgcn_mfma_f32_16x16x32_bf16(a1, breg[kk], acc[1], 0, 0, 0);
        acc[2] = __builtin_amdgcn_mfma_f32_16x16x32_bf16(a2, breg[kk], acc[2], 0, 0, 0);
        acc[3] = __builtin_amdgcn_mfma_f32_16x16x32_bf16(a3, breg[kk], acc[3], 0, 0, 0);
      }
    }

    // stage partial gate sums: gt[kw][batch][col]
#pragma unroll
    for (int bt = 0; bt < 4; ++bt)
#pragma unroll
      for (int r = 0; r < 4; ++r)
        gt[kw][bt * 16 + rq + r][ct * 16 + fr] = acc[bt][r];
    __syncthreads();

    // cell
    float hn[2];
#pragma unroll
    for (int r = 0; r < 2; ++r) {
      int jj = cj + r;
      float gi = gt[0][cb][jj]      + gt[1][cb][jj]      + gx[0][r] + bsr[0][r];
      float gf = gt[0][cb][8 + jj]  + gt[1][cb][8 + jj]  + gx[1][r] + bsr[1][r];
      float gg = gt[0][cb][16 + jj] + gt[1][cb][16 + jj] + gx[2][r] + bsr[2][r];
      float go = gt[0][cb][24 + jj] + gt[1][cb][24 + jj] + gx[3][r] + bsr[3][r];
      float cn = sigf(gf) * creg[r] + sigf(gi) * tanhf(gg);
      creg[r] = cn;
      hn[r] = sigf(go) * tanhf(cn);
    }
    bf16* wb = (t & 1) ? hb1 : hb0;
    wb[cb * 1024 + j0 + cj]     = (bf16)hn[0];
    wb[cb * 1024 + j0 + cj + 1] = (bf16)hn[1];
    if (Sout) {
      Sout[(size_t)t * 65536 + cb * 1024 + j0 + cj]     = (bf16)hn[0];
      Sout[(size_t)t * 65536 + cb * 1024 + j0 + cj + 1] = (bf16)hn[1];
    }
    if (Hfin && t == T - 1) {
      Hfin[cb * 1024 + j0 + cj]     = (bf16)tanhf(hn[0]);
      Hfin[cb * 1024 + j0 + cj + 1] = (bf16)tanhf(hn[1]);
    }

    // grid barrier (monotonic counter, agent scope)
    __syncthreads();
    if (tid == 0) {
      __threadfence();
      __hip_atomic_fetch_add(bar, 1u, __ATOMIC_RELEASE, __HIP_MEMORY_SCOPE_AGENT);
      ++gen;
      unsigned tgt = gen * nwg;
      while (__hip_atomic_load(bar, __ATOMIC_ACQUIRE, __HIP_MEMORY_SCOPE_AGENT) < tgt)
        __builtin_amdgcn_s_sleep(2);
      __threadfence();
    }
    __syncthreads();
  }
}

// ---------------- host orchestration ----------------
extern "C" void kernel_launch(void* const* d_in, const int* in_sizes, int n_in,
                              void* d_out, int out_size, void* d_ws, size_t ws_size,
                              hipStream_t stream) {
  (void)in_sizes; (void)n_in; (void)out_size; (void)ws_size;
  const float* x      = (const float*)d_in[0];
  const float* dec_c0 = (const float*)d_in[1];
  const float* W_f32[9] = { (const float*)d_in[2],  (const float*)d_in[3],
                            (const float*)d_in[5],  (const float*)d_in[6],
                            (const float*)d_in[8],  (const float*)d_in[9],
                            (const float*)d_in[11], (const float*)d_in[12],
                            (const float*)d_in[14] };
  const float* eb0 = (const float*)d_in[4];
  const float* eb1 = (const float*)d_in[7];
  const float* db0 = (const float*)d_in[10];
  const float* db1 = (const float*)d_in[13];
  const float* fcb = (const float*)d_in[15];
  float* out = (float*)d_out;

  const int H = 1024, I = 512, T = 128, B = 64;
  const int BH = B * H;
  const size_t TBI = (size_t)T * B * I;
  const size_t TBH = (size_t)T * B * H;

  char* p = (char*)d_ws;
  auto alloc = [&](size_t bytes) -> char* {
    char* r = p; p += (bytes + 255) & ~(size_t)255; return r;
  };
  const int wsizes[9] = { 4 * H * I, 4 * H * H, 4 * H * H, 4 * H * H,
                          4 * H * I, 4 * H * H, 4 * H * H, 4 * H * H, I * H };
  bf16* Wbf[9];
  for (int i = 0; i < 9; ++i) Wbf[i] = (bf16*)alloc((size_t)wsizes[i] * 2);
  bf16* xe = (bf16*)alloc(TBI * 2);
  bf16* xd = (bf16*)alloc(TBI * 2);
  bf16* G  = (bf16*)alloc((size_t)T * B * 4 * H * 2);
  bf16* S0 = (bf16*)alloc(TBH * 2);
  bf16* S1 = (bf16*)alloc(TBH * 2);
  bf16* hb0 = (bf16*)alloc((size_t)BH * 2);
  bf16* hb1 = (bf16*)alloc((size_t)BH * 2);
  bf16* henc0 = (bf16*)alloc((size_t)BH * 2);
  bf16* henc1 = (bf16*)alloc((size_t)BH * 2);
  unsigned* bars = (unsigned*)alloc(256);

  zero_bars_k<<<1, 64, 0, stream>>>(bars);
  for (int i = 0; i < 9; ++i) {
    int n = wsizes[i];
    cast_bf_k<<<(n + 255) / 256, 256, 0, stream>>>(W_f32[i], Wbf[i], n);
  }
  prep_x_k<<<(int)((TBI + 255) / 256), 256, 0, stream>>>(x, xe, xd);

  auto coop = [&](const bf16* Gp, const bf16* Wp, const float* bp, const bf16* h0p,
                  const float* c0p, bf16* So, bf16* Hf, unsigned* barp) {
    int Tc = T;
    bf16* b0 = hb0; bf16* b1 = hb1;
    void* args[] = { (void*)&Gp, (void*)&Wp, (void*)&bp, (void*)&h0p, (void*)&c0p,
                     (void*)&b0, (void*)&b1, (void*)&So, (void*)&Hf, (void*)&barp,
                     (void*)&Tc };
    hipLaunchCooperativeKernel((void*)lstm_seq_k, dim3(128), dim3(256), args, 0, stream);
  };

  // ---- encoder layer 0 ----
  gemm_bt_k<<<dim3(32, 64), 256, 0, stream>>>(xe, Wbf[0], G, nullptr, nullptr, 8192, 4096, 512, 0);
  coop(G, Wbf[1], eb0, nullptr, nullptr, S0, henc0, bars + 0);

  // ---- encoder layer 1 ----
  gemm_bt_k<<<dim3(32, 64), 256, 0, stream>>>(S0, Wbf[2], G, nullptr, nullptr, 8192, 4096, 1024, 0);
  coop(G, Wbf[3], eb1, nullptr, nullptr, nullptr, henc1, bars + 1);

  // ---- decoder layer 0 ----
  gemm_bt_k<<<dim3(32, 64), 256, 0, stream>>>(xd, Wbf[4], G, nullptr, nullptr, 8192, 4096, 512, 0);
  coop(G, Wbf[5], db0, henc0, dec_c0, S0, nullptr, bars + 2);

  // ---- decoder layer 1 ----
  gemm_bt_k<<<dim3(32, 64), 256, 0, stream>>>(S0, Wbf[6], G, nullptr, nullptr, 8192, 4096, 1024, 0);
  coop(G, Wbf[7], db1, henc1, dec_c0 + BH, S1, nullptr, bars + 3);

  // ---- FC: sigmoid(S1 @ fcW^T + fcb), permute [t,b]->[b,t] ----
  gemm_bt_k<<<dim3(4, 64), 256, 0, stream>>>(S1, Wbf[8], nullptr, out, fcb, 8192, 512, 1024, 1);
}

// Round 3
// 7065.222 us; speedup vs baseline: 2.1099x; 2.1099x over previous
//
#include <hip/hip_runtime.h>
#include <cmath>

typedef __bf16 bf16;
typedef float f32x4 __attribute__((ext_vector_type(4)));
typedef bf16 bf16x8 __attribute__((ext_vector_type(8)));
typedef bf16 bf16x2 __attribute__((ext_vector_type(2)));

#define DEVINL __device__ __forceinline__

DEVINL void gload_lds16(const void* g, void* l) {
  __builtin_amdgcn_global_load_lds(
      (const __attribute__((address_space(1))) void*)g,
      (__attribute__((address_space(3))) void*)l, 16, 0, 0);
}

DEVINL float sigf(float x) { return 1.f / (1.f + __expf(-x)); }

// ---------------- cast / prep kernels ----------------
__global__ void cast_bf_k(const float* __restrict__ in, bf16* __restrict__ out, int n) {
  int i = blockIdx.x * blockDim.x + threadIdx.x;
  if (i < n) out[i] = (bf16)in[i];
}

// out[row*2048 + k] = k<1024 ? Wih[row*1024+k] : Whh[row*1024+k-1024]
__global__ void cast_cat_k(const float* __restrict__ Wih, const float* __restrict__ Whh,
                           bf16* __restrict__ out, int n) {
  int idx = blockIdx.x * blockDim.x + threadIdx.x;
  if (idx >= n) return;
  int k = idx & 2047;
  int row = idx >> 11;
  out[idx] = (bf16)((k < 1024) ? Wih[row * 1024 + k] : Whh[row * 1024 + (k - 1024)]);
}

__global__ void prep_x_k(const float* __restrict__ x, bf16* __restrict__ xe,
                         bf16* __restrict__ xd) {
  int idx = blockIdx.x * blockDim.x + threadIdx.x;  // T*B*I = 4194304
  if (idx >= 128 * 64 * 512) return;
  int i = idx & 511;
  int b = (idx >> 9) & 63;
  int t = idx >> 15;
  xe[idx] = (bf16)x[(size_t)b * 65536 + (size_t)t * 512 + i];
  xd[idx] = (t == 0) ? (bf16)0.f
                     : (bf16)x[(size_t)b * 65536 + (size_t)(t - 1) * 512 + i];
}

// ---------------- big GEMM: C[M,N] = A[M,K] @ W[N,K]^T (bf16 in, f32 acc) ----------
__global__ __launch_bounds__(256) void gemm_bt_k(
    const bf16* __restrict__ A, const bf16* __restrict__ Bw,
    bf16* __restrict__ Cbf, float* __restrict__ Cf32, const float* __restrict__ bias,
    int M, int N, int K, int mode) {
  __shared__ __attribute__((aligned(16))) bf16 As[128 * 32];
  __shared__ __attribute__((aligned(16))) bf16 Bs[128 * 32];
  const int tid = threadIdx.x;
  const int lane = tid & 63;
  const int wave = tid >> 6;
  const int wm = wave >> 1, wn = wave & 1;
  const int m0 = blockIdx.y * 128;
  const int n0 = blockIdx.x * 128;

  f32x4 acc[4][4];
  for (int i = 0; i < 4; ++i)
    for (int j = 0; j < 4; ++j) acc[i][j] = 0;

  const int r1 = tid >> 2;
  const int kc = (tid & 3) * 8;
  const int fr = lane & 15;
  const int fk = (lane >> 4) * 8;

  for (int k0 = 0; k0 < K; k0 += 32) {
    gload_lds16(A + (size_t)(m0 + r1) * K + k0 + kc, As + tid * 8);
    gload_lds16(A + (size_t)(m0 + 64 + r1) * K + k0 + kc, As + 2048 + tid * 8);
    gload_lds16(Bw + (size_t)(n0 + r1) * K + k0 + kc, Bs + tid * 8);
    gload_lds16(Bw + (size_t)(n0 + 64 + r1) * K + k0 + kc, Bs + 2048 + tid * 8);
    __syncthreads();
    bf16x8 af[4], bw[4];
    for (int i = 0; i < 4; ++i)
      af[i] = *(const bf16x8*)(As + (wm * 64 + i * 16 + fr) * 32 + fk);
    for (int j = 0; j < 4; ++j)
      bw[j] = *(const bf16x8*)(Bs + (wn * 64 + j * 16 + fr) * 32 + fk);
    for (int i = 0; i < 4; ++i)
      for (int j = 0; j < 4; ++j)
        acc[i][j] = __builtin_amdgcn_mfma_f32_16x16x32_bf16(af[i], bw[j], acc[i][j], 0, 0, 0);
    __syncthreads();
  }

  const int col16 = lane & 15;
  const int rq = (lane >> 4) * 4;
  for (int i = 0; i < 4; ++i)
    for (int j = 0; j < 4; ++j)
      for (int r = 0; r < 4; ++r) {
        int row = m0 + wm * 64 + i * 16 + rq + r;
        int col = n0 + wn * 64 + j * 16 + col16;
        float v = acc[i][j][r];
        if (mode == 0) {
          Cbf[(size_t)row * N + col] = (bf16)v;
        } else {
          v = sigf(v + bias[col]);
          int b = row & 63, t = row >> 6;
          Cf32[(size_t)b * (128 * 512) + (size_t)t * 512 + col] = v;
        }
      }
}

// ---------------- paired two-layer LSTM step ----------------
// Grid 256 WGs x 256 thr. WGs 0..127: layer A at step tA (K=1024, gates from
// precomputed GA + h@WhhA^T). WGs 128..255: layer B at step tB = tA-1
// (K=2048 over concat[S_A[tB], h_B] @ WcatB^T; input-side GEMM folded in).
// All cross-half deps are to the PREVIOUS dispatch -> kernel-boundary sync.
// Per WG: 8 hidden cols x 4 gates = 32 gate-cols x 64 batch. Waves: ct=wave&1
// (16-col tile), kw=wave>>1 (K half). B-frags global->VGPR (L2-hot, disjoint
// per WG). A-frags straight from global h/S. No barriers in k-loop.
__global__ __launch_bounds__(256, 1) void step_pair_k(
    const bf16* __restrict__ GA, const bf16* __restrict__ WhhA,
    const float* __restrict__ biasA, const bf16* __restrict__ hA0,
    const float* __restrict__ cA0, bf16* __restrict__ hAb0, bf16* __restrict__ hAb1,
    float* __restrict__ cA, bf16* __restrict__ SoutA, bf16* __restrict__ HfinA,
    const bf16* __restrict__ SinB, const bf16* __restrict__ WcatB,
    const float* __restrict__ biasB, const bf16* __restrict__ hB0,
    const float* __restrict__ cB0, bf16* __restrict__ hBb0, bf16* __restrict__ hBb1,
    float* __restrict__ cB, bf16* __restrict__ SoutB, bf16* __restrict__ HfinB,
    int tA, int tB) {
  __shared__ float gt[2][64][33];
  const int tid = threadIdx.x;
  const int lane = tid & 63;
  const int wave = tid >> 6;
  const int ct = wave & 1;
  const int kw = wave >> 1;
  const int half = blockIdx.x >> 7;
  const int j0 = (blockIdx.x & 127) * 8;
  const int fr = lane & 15;
  const int fk = (lane >> 4) * 8;
  const int rq = (lane >> 4) * 4;
  const int ccol = ct * 16 + fr;                       // gate-col 0..31
  const int nrow = (ccol >> 3) * 1024 + j0 + (ccol & 7);  // weight row
  const int cb = tid >> 2;                             // cell batch
  const int cj = (tid & 3) * 2;                        // cell col pair

  int t;
  const float* bias;
  const float* c0;
  float* cst;
  bf16 *wb, *Sout, *Hfin;
  float gx[4][2] = {{0, 0}, {0, 0}, {0, 0}, {0, 0}};
  f32x4 acc[4];
  acc[0] = 0; acc[1] = 0; acc[2] = 0; acc[3] = 0;

  if (half == 0) {
    if (tA < 0) return;
    t = tA; bias = biasA; c0 = cA0; cst = cA; Sout = SoutA; Hfin = HfinA;
    wb = (t & 1) ? hAb1 : hAb0;
    const bf16* Gt = GA + (size_t)t * (64 * 4096) + (size_t)cb * 4096;
#pragma unroll
    for (int g = 0; g < 4; ++g) {
      bf16x2 g2 = *(const bf16x2*)(Gt + g * 1024 + j0 + cj);
      gx[g][0] = (float)g2.x;
      gx[g][1] = (float)g2.y;
    }
    const bf16* wp = WhhA + (size_t)nrow * 1024 + kw * 512 + fk;
    const bf16* hp = (t == 0) ? hA0 : ((t & 1) ? hAb0 : hAb1);
    if (hp) {
      const bf16* ap = hp + fr * 1024 + kw * 512 + fk;
#pragma unroll
      for (int kk = 0; kk < 16; ++kk) {
        bf16x8 bw = *(const bf16x8*)(wp + kk * 32);
        bf16x8 a0 = *(const bf16x8*)(ap + kk * 32);
        bf16x8 a1 = *(const bf16x8*)(ap + 16 * 1024 + kk * 32);
        bf16x8 a2 = *(const bf16x8*)(ap + 32 * 1024 + kk * 32);
        bf16x8 a3 = *(const bf16x8*)(ap + 48 * 1024 + kk * 32);
        acc[0] = __builtin_amdgcn_mfma_f32_16x16x32_bf16(a0, bw, acc[0], 0, 0, 0);
        acc[1] = __builtin_amdgcn_mfma_f32_16x16x32_bf16(a1, bw, acc[1], 0, 0, 0);
        acc[2] = __builtin_amdgcn_mfma_f32_16x16x32_bf16(a2, bw, acc[2], 0, 0, 0);
        acc[3] = __builtin_amdgcn_mfma_f32_16x16x32_bf16(a3, bw, acc[3], 0, 0, 0);
      }
    }
  } else {
    if (tB < 0) return;
    t = tB; bias = biasB; c0 = cB0; cst = cB; Sout = SoutB; Hfin = HfinB;
    wb = (t & 1) ? hBb1 : hBb0;
    const bf16* wp = WcatB + (size_t)nrow * 2048 + kw * 1024 + fk;
    // kw=0: k 0..1023 from S_A[t]; kw=1: k 1024..2047 from h_B(t-1)
    const bf16* src = (kw == 0) ? (SinB + (size_t)t * 65536)
                                : ((t == 0) ? hB0 : ((t & 1) ? hBb0 : hBb1));
    if (src) {
      const bf16* ap = src + fr * 1024 + fk;
#pragma unroll
      for (int kk = 0; kk < 32; ++kk) {
        bf16x8 bw = *(const bf16x8*)(wp + kk * 32);
        bf16x8 a0 = *(const bf16x8*)(ap + kk * 32);
        bf16x8 a1 = *(const bf16x8*)(ap + 16 * 1024 + kk * 32);
        bf16x8 a2 = *(const bf16x8*)(ap + 32 * 1024 + kk * 32);
        bf16x8 a3 = *(const bf16x8*)(ap + 48 * 1024 + kk * 32);
        acc[0] = __builtin_amdgcn_mfma_f32_16x16x32_bf16(a0, bw, acc[0], 0, 0, 0);
        acc[1] = __builtin_amdgcn_mfma_f32_16x16x32_bf16(a1, bw, acc[1], 0, 0, 0);
        acc[2] = __builtin_amdgcn_mfma_f32_16x16x32_bf16(a2, bw, acc[2], 0, 0, 0);
        acc[3] = __builtin_amdgcn_mfma_f32_16x16x32_bf16(a3, bw, acc[3], 0, 0, 0);
      }
    }
  }

  // stage partial gate sums: gt[kw][batch][gate-col]
#pragma unroll
  for (int bt = 0; bt < 4; ++bt)
#pragma unroll
    for (int r = 0; r < 4; ++r)
      gt[kw][bt * 16 + rq + r][ct * 16 + fr] = acc[bt][r];
  __syncthreads();

  // cell update: thread owns (b=cb, cols j0+cj, j0+cj+1)
  float creg[2];
#pragma unroll
  for (int r = 0; r < 2; ++r) {
    int off = cb * 1024 + j0 + cj + r;
    creg[r] = (t == 0) ? (c0 ? c0[off] : 0.f) : cst[off];
  }
  float hn[2];
#pragma unroll
  for (int r = 0; r < 2; ++r) {
    int jj = cj + r;
    int j = j0 + jj;
    float gi = gt[0][cb][jj]      + gt[1][cb][jj]      + gx[0][r] + bias[j];
    float gf = gt[0][cb][8 + jj]  + gt[1][cb][8 + jj]  + gx[1][r] + bias[1024 + j];
    float gg = gt[0][cb][16 + jj] + gt[1][cb][16 + jj] + gx[2][r] + bias[2048 + j];
    float go = gt[0][cb][24 + jj] + gt[1][cb][24 + jj] + gx[3][r] + bias[3072 + j];
    float cn = sigf(gf) * creg[r] + sigf(gi) * tanhf(gg);
    cst[cb * 1024 + j0 + cj + r] = cn;
    hn[r] = sigf(go) * tanhf(cn);
  }
  bf16x2 h2; h2.x = (bf16)hn[0]; h2.y = (bf16)hn[1];
  *(bf16x2*)(wb + cb * 1024 + j0 + cj) = h2;
  if (Sout) *(bf16x2*)(Sout + (size_t)t * 65536 + cb * 1024 + j0 + cj) = h2;
  if (Hfin && t == 127) {
    bf16x2 e2; e2.x = (bf16)tanhf(hn[0]); e2.y = (bf16)tanhf(hn[1]);
    *(bf16x2*)(Hfin + cb * 1024 + j0 + cj) = e2;
  }
}

// ---------------- host orchestration ----------------
extern "C" void kernel_launch(void* const* d_in, const int* in_sizes, int n_in,
                              void* d_out, int out_size, void* d_ws, size_t ws_size,
                              hipStream_t stream) {
  (void)in_sizes; (void)n_in; (void)out_size; (void)ws_size;
  const float* x      = (const float*)d_in[0];
  const float* dec_c0 = (const float*)d_in[1];
  const float* eWih0 = (const float*)d_in[2];
  const float* eWhh0 = (const float*)d_in[3];
  const float* eb0   = (const float*)d_in[4];
  const float* eWih1 = (const float*)d_in[5];
  const float* eWhh1 = (const float*)d_in[6];
  const float* eb1   = (const float*)d_in[7];
  const float* dWih0 = (const float*)d_in[8];
  const float* dWhh0 = (const float*)d_in[9];
  const float* db0   = (const float*)d_in[10];
  const float* dWih1 = (const float*)d_in[11];
  const float* dWhh1 = (const float*)d_in[12];
  const float* db1   = (const float*)d_in[13];
  const float* fcW   = (const float*)d_in[14];
  const float* fcb   = (const float*)d_in[15];
  float* out = (float*)d_out;

  const int H = 1024, I = 512, T = 128, B = 64;
  const int BH = B * H;
  const size_t TBI = (size_t)T * B * I;
  const size_t TBH = (size_t)T * B * H;

  char* p = (char*)d_ws;
  auto alloc = [&](size_t bytes) -> char* {
    char* r = p; p += (bytes + 255) & ~(size_t)255; return r;
  };
  bf16* Wih_e0 = (bf16*)alloc((size_t)4 * H * I * 2);
  bf16* Whh_e0 = (bf16*)alloc((size_t)4 * H * H * 2);
  bf16* Wcat_e1 = (bf16*)alloc((size_t)4 * H * 2 * H * 2);
  bf16* Wih_d0 = (bf16*)alloc((size_t)4 * H * I * 2);
  bf16* Whh_d0 = (bf16*)alloc((size_t)4 * H * H * 2);
  bf16* Wcat_d1 = (bf16*)alloc((size_t)4 * H * 2 * H * 2);
  bf16* Wfc = (bf16*)alloc((size_t)I * H * 2);
  bf16* xe = (bf16*)alloc(TBI * 2);
  bf16* xd = (bf16*)alloc(TBI * 2);
  bf16* G  = (bf16*)alloc((size_t)T * B * 4 * H * 2);
  bf16* S0 = (bf16*)alloc(TBH * 2);
  bf16* S1 = (bf16*)alloc(TBH * 2);
  bf16* hAb0 = (bf16*)alloc((size_t)BH * 2);
  bf16* hAb1 = (bf16*)alloc((size_t)BH * 2);
  bf16* hBb0 = (bf16*)alloc((size_t)BH * 2);
  bf16* hBb1 = (bf16*)alloc((size_t)BH * 2);
  float* cA = (float*)alloc((size_t)BH * 4);
  float* cB = (float*)alloc((size_t)BH * 4);
  bf16* henc0 = (bf16*)alloc((size_t)BH * 2);
  bf16* henc1 = (bf16*)alloc((size_t)BH * 2);

  // weight prep
  cast_bf_k<<<(4 * H * I + 255) / 256, 256, 0, stream>>>(eWih0, Wih_e0, 4 * H * I);
  cast_bf_k<<<(4 * H * H + 255) / 256, 256, 0, stream>>>(eWhh0, Whh_e0, 4 * H * H);
  cast_cat_k<<<(8 * H * H + 255) / 256, 256, 0, stream>>>(eWih1, eWhh1, Wcat_e1, 8 * H * H);
  cast_bf_k<<<(4 * H * I + 255) / 256, 256, 0, stream>>>(dWih0, Wih_d0, 4 * H * I);
  cast_bf_k<<<(4 * H * H + 255) / 256, 256, 0, stream>>>(dWhh0, Whh_d0, 4 * H * H);
  cast_cat_k<<<(8 * H * H + 255) / 256, 256, 0, stream>>>(dWih1, dWhh1, Wcat_d1, 8 * H * H);
  cast_bf_k<<<(I * H + 255) / 256, 256, 0, stream>>>(fcW, Wfc, I * H);
  prep_x_k<<<(int)((TBI + 255) / 256), 256, 0, stream>>>(x, xe, xd);

  // ---- encoder pre-GEMM (layer 0 input side) ----
  gemm_bt_k<<<dim3(32, 64), 256, 0, stream>>>(xe, Wih_e0, G, nullptr, nullptr,
                                              8192, 4096, 512, 0);
  // ---- encoder: L0 + L1 pipelined, skew 1 ----
  for (int d = 0; d <= T; ++d) {
    int tA = (d < T) ? d : -1;
    int tB = d - 1;
    step_pair_k<<<256, 256, 0, stream>>>(
        G, Whh_e0, eb0, nullptr, nullptr, hAb0, hAb1, cA, S0, henc0,
        S0, Wcat_e1, eb1, nullptr, nullptr, hBb0, hBb1, cB, nullptr, henc1,
        tA, tB);
  }
  // ---- decoder pre-GEMM (layer 0 input side) ----
  gemm_bt_k<<<dim3(32, 64), 256, 0, stream>>>(xd, Wih_d0, G, nullptr, nullptr,
                                              8192, 4096, 512, 0);
  // ---- decoder: L0 + L1 pipelined, skew 1 ----
  for (int d = 0; d <= T; ++d) {
    int tA = (d < T) ? d : -1;
    int tB = d - 1;
    step_pair_k<<<256, 256, 0, stream>>>(
        G, Whh_d0, db0, henc0, dec_c0, hAb0, hAb1, cA, S0, nullptr,
        S0, Wcat_d1, db1, henc1, dec_c0 + BH, hBb0, hBb1, cB, S1, nullptr,
        tA, tB);
  }
  // ---- FC: sigmoid(S1 @ fcW^T + fcb), permute [t,b]->[b,t] ----
  gemm_bt_k<<<dim3(4, 64), 256, 0, stream>>>(S1, Wfc, nullptr, out, fcb,
                                             8192, 512, 1024, 1);
}